// Round 10
// baseline (4300.380 us; speedup 1.0000x reference)
//
#include <hip/hip_runtime.h>
#include <cstddef>

// Problem constants (from reference setup_inputs)
#define S_ 512
#define B_ 64
#define I_ 256
#define H_ 1024

#define NG 8     // batch groups (8 batches each)
#define GB 8     // batches per group
#define JT 32    // j rows per block
#define GBLK 32  // blocks per group (= 1024/JT)

// ---------------------------------------------------------------------------
// Transpose: out[c*R + r] = in[r*C + c].  R,C multiples of 32. (Wx only)
// ---------------------------------------------------------------------------
__global__ __launch_bounds__(256) void transpose_k(const float* __restrict__ in,
                                                   float* __restrict__ out,
                                                   int R, int C) {
  __shared__ float t[32][33];
  int c0 = blockIdx.x * 32, r0 = blockIdx.y * 32;
  int x = threadIdx.x & 31, y = threadIdx.x >> 5;
  for (int i = 0; i < 32; i += 8) {
    t[y + i][x] = in[(size_t)(r0 + y + i) * C + (c0 + x)];
  }
  __syncthreads();
  for (int i = 0; i < 32; i += 8) {
    out[(size_t)(c0 + y + i) * R + (r0 + x)] = t[x][y + i];
  }
}

// ---------------------------------------------------------------------------
// xproj: out[m*H + j] = dot(x[m, 0:256], WxT[:, j]) + bx[j]
// 8 m-rows per block.  grid = (H/256 = 4, S*B/8 = 4096)
// ---------------------------------------------------------------------------
__global__ __launch_bounds__(256) void xproj_kernel(const float* __restrict__ x,
                                                    const float* __restrict__ WxT,
                                                    const float* __restrict__ bx,
                                                    float* __restrict__ out) {
  __shared__ float xs[8][I_];
  int tid = threadIdx.x;
  int j = blockIdx.x * 256 + tid;
  size_t m0 = (size_t)blockIdx.y * 8;
  const float* xrow = x + m0 * I_;
  #pragma unroll
  for (int r = 0; r < 8; ++r) xs[r][tid] = xrow[(size_t)r * I_ + tid];
  __syncthreads();

  float bj = bx[j];
  float a[8];
  #pragma unroll
  for (int r = 0; r < 8; ++r) a[r] = bj;
  const float* wp = WxT + j;
  for (int k = 0; k < I_; k += 4) {
    float w0 = wp[(size_t)(k + 0) * H_];
    float w1 = wp[(size_t)(k + 1) * H_];
    float w2 = wp[(size_t)(k + 2) * H_];
    float w3 = wp[(size_t)(k + 3) * H_];
    #pragma unroll
    for (int r = 0; r < 8; ++r) {
      float4 v = *(const float4*)&xs[r][k];
      a[r] += w0 * v.x + w1 * v.y + w2 * v.z + w3 * v.w;
    }
  }
  #pragma unroll
  for (int r = 0; r < 8; ++r) out[(m0 + r) * H_ + j] = a[r];
}

// ---------------------------------------------------------------------------
// Persistent recurrence kernel, W-in-registers, grid = 256 x 512 threads.
//   __launch_bounds__(512, 2): 2 waves/SIMD floor -> 128-VGPR budget, so the
//   64-VGPR Wreg tile is genuinely register-resident (round 8's VGPR_Count=72
//   proved the compiler was spilling/rematerializing it without this).
//   256 blocks = 32 j-tiles x 8 batch-groups; block tile = 32 j x 8 b.
//   thread (jj = tid>>4, ks = tid&15): holds Wh[j0+jj][ks*64 .. +64) in 16
//   float4 VGPRs forever.  Per step: stage h_prev (8 x 1024 f32 = 32KB) into
//   XOR-swizzled LDS (float4 slot f stored at f ^ ((f>>4)&7)); logical col
//   kb+i is read at PHYSICAL kb + (i^ksw) paired with Wreg[i] (XOR once).
//   Partial dot over the thread's 64-wide k-range for all 8 batches; 4-stage
//   shfl_xor reduce over the 16 ks lanes; lane ks<8 owns output (b0+ks, j).
//   Sync: per-group flag array (32 flags), plain sc1 stores + parallel poll.
// ---------------------------------------------------------------------------
__global__ __launch_bounds__(512, 2) void rnn_persistent(
    const float* __restrict__ Wh, const float* __restrict__ bh,
    float* __restrict__ out, unsigned* __restrict__ flags) {
  __shared__ float4 Hs4[GB * 256];  // 32 KB; float4 slot f at f ^ ((f>>4)&7)

  const int tid = threadIdx.x;
  const int g  = blockIdx.x & 7;   // batch-group
  const int jt = blockIdx.x >> 3;  // j-tile (0..31)
  const int j0 = jt * JT, b0 = g * GB;
  const int jj = tid >> 4;         // 0..31 : j row within tile
  const int ks = tid & 15;         // 0..15 : k-split (64 floats each)
  const int ksw = ks & 7;

  // ---- permanent W fragment: Wh[j0+jj][ks*64 .. +64) = 16 float4 ----
  float4 Wreg[16];
  {
    const float4* wp = (const float4*)(Wh + (size_t)(j0 + jj) * H_) + ks * 16;
    #pragma unroll
    for (int i = 0; i < 16; ++i) Wreg[i] = wp[i];
  }
  const float bh_j = bh[j0 + jj];
  // lane ks = b (b < 8) owns output (b0+b, j0+jj); ks>=8 reads a dup row.
  const size_t oidx = (size_t)(b0 + ksw) * H_ + (size_t)(j0 + jj);
  float* const out_last = out + (size_t)S_ * B_ * H_;
  unsigned* const flagg = flags + (size_t)g * GBLK;

  for (int t = 0; t < S_; ++t) {
    float* orow = out + (size_t)t * B_ * H_;
    float xv = orow[oidx];  // xproj_t (written pre-kernel, line untouched since)

    float s = 0.f;
    if (t > 0) {
      // ---- stage h_{t-1}: 4 batched dwordx4 sc1 loads, one vmcnt drain ----
      const float* hsrc =
          (const float*)(out + (size_t)(t - 1) * B_ * H_ + (size_t)b0 * H_);
      float4 hv[4];
      #pragma unroll
      for (int q = 0; q < 4; ++q) {
        const float* ap = hsrc + (size_t)(q * 512 + tid) * 4;
        asm volatile("global_load_dwordx4 %0, %1, off sc1"
                     : "=v"(hv[q]) : "v"(ap));
      }
      asm volatile("s_waitcnt vmcnt(0)" ::: "memory");
      __builtin_amdgcn_sched_barrier(0);
      #pragma unroll
      for (int q = 0; q < 4; ++q) {
        int f = q * 512 + tid;
        Hs4[f ^ ((f >> 4) & 7)] = hv[q];
      }
      __syncthreads();

      // ---- partial dot: k in [ks*64, +64), all 8 batches ----
      float acc[8] = {0.f, 0.f, 0.f, 0.f, 0.f, 0.f, 0.f, 0.f};
      const int kb = ks * 16;  // float4 base within a row
      #pragma unroll
      for (int i = 0; i < 16; ++i) {
        const int l0 = kb + (i ^ ksw);  // PHYSICAL slot of logical col kb+i
        const float4 w = Wreg[i];       // W for logical col kb+i (XOR once!)
        #pragma unroll
        for (int b = 0; b < 8; ++b) {
          float4 h = Hs4[b * 256 + l0];
          acc[b] += w.x * h.x + w.y * h.y + w.z * h.z + w.w * h.w;
        }
      }
      // ---- reduce over the 16 ks lanes (lane bits 0..3), in-register ----
      #pragma unroll
      for (int b = 0; b < 8; ++b) {
        float v = acc[b];
        v += __shfl_xor(v, 1, 64);
        v += __shfl_xor(v, 2, 64);
        v += __shfl_xor(v, 4, 64);
        v += __shfl_xor(v, 8, 64);
        acc[b] = v;
      }
      // lane ks = b picks acc[b] (static-index select, no scratch)
      float sv = acc[0];
      #pragma unroll
      for (int b = 1; b < 8; ++b) sv = (ks == b) ? acc[b] : sv;
      s = sv;
    }

    if (ks < GB) {
      float hval = tanhf(s + bh_j + xv);
      if (t == S_ - 1) out_last[oidx] = hval;
      __hip_atomic_store(&orow[oidx], hval, __ATOMIC_RELAXED,
                         __HIP_MEMORY_SCOPE_AGENT);
    }

    if (t < S_ - 1) {
      asm volatile("s_waitcnt vmcnt(0)" ::: "memory");  // drain sc1 h stores
      __syncthreads();  // all waves drained; Hs4 safe to overwrite next step
      if (tid == 0) {
        __hip_atomic_store(&flagg[jt], (unsigned)(t + 1), __ATOMIC_RELAXED,
                           __HIP_MEMORY_SCOPE_AGENT);
      }
      if (tid < 64) {
        unsigned* fp = &flagg[tid & 31];
        const unsigned tgt = (unsigned)(t + 1);
        while (__hip_atomic_load(fp, __ATOMIC_RELAXED,
                                 __HIP_MEMORY_SCOPE_AGENT) < tgt)
          __builtin_amdgcn_s_sleep(1);
      }
      __syncthreads();
    }
  }
}

// ---------------------------------------------------------------------------
// Launch. ws layout: WxT (256*1024 f32 = 1MB) | flags (8 x 32 u32)
// If the cooperative launch is refused (validation quirk), fall back to a
// plain launch of the same shape: 256 blocks on 256 CUs are all-resident.
// ---------------------------------------------------------------------------
extern "C" void kernel_launch(void* const* d_in, const int* in_sizes, int n_in,
                              void* d_out, int out_size, void* d_ws, size_t ws_size,
                              hipStream_t stream) {
  const float* x  = (const float*)d_in[0];
  const float* Wx = (const float*)d_in[1];
  const float* bx = (const float*)d_in[2];
  const float* Wh = (const float*)d_in[3];
  const float* bh = (const float*)d_in[4];
  float* out = (float*)d_out;
  float* WxT = (float*)d_ws;                            // [I_][H_]
  unsigned* flags = (unsigned*)(WxT + (size_t)I_ * H_); // 8 x 32

  (void)hipMemsetAsync(flags, 0, NG * GBLK * sizeof(unsigned), stream);
  hipLaunchKernelGGL(transpose_k, dim3(I_ / 32, H_ / 32), dim3(256), 0, stream,
                     Wx, WxT, H_, I_);
  hipLaunchKernelGGL(xproj_kernel, dim3(H_ / 256, (S_ * B_) / 8), dim3(256), 0, stream,
                     x, WxT, bx, out);

  void* args[] = {(void*)&Wh, (void*)&bh, (void*)&out, (void*)&flags};
  hipError_t e = hipLaunchCooperativeKernel((const void*)rnn_persistent,
                                            dim3(256), dim3(512), args, 0, stream);
  if (e != hipSuccess) {
    hipLaunchKernelGGL(rnn_persistent, dim3(256), dim3(512), 0, stream,
                       Wh, bh, out, flags);
  }
}